// Round 6
// baseline (176.421 us; speedup 1.0000x reference)
//
#include <hip/hip_runtime.h>
#include <hip/hip_bf16.h>

// N=50000, E=600000, D=128, R=500 — fp32 inputs, bf16-tolerant check (thr 0.535).
// out = relu( (gather_sum(h[src]+emb[etype]) * norm) @ Wn + h @ (deg>0 ? Wl : We) )
// R6: gather = 2 interleaved linked-list chains per 16-lane group (2x MLP on
// the dependent list loads, ~25% less divergence waste); deg==0 fixup fused
// into GEMM epilogue (ballot on head[row]<0, rare fp32 slow path). 4 kernels.

#define DIM 128

typedef __attribute__((ext_vector_type(8))) short bf16x8_t;
typedef __attribute__((ext_vector_type(4))) float f32x4_t;

__device__ inline ushort f2bf(float f) {
    __hip_bfloat16 b = __float2bfloat16(f);
    return *reinterpret_cast<ushort*>(&b);
}
__device__ inline float bf2f(ushort u) {
    unsigned v = ((unsigned)u) << 16;
    return __uint_as_float(v);
}
__device__ inline uint4 cvt8(const float4& a, const float4& b) {
    uint4 o;
    o.x = f2bf(a.x) | ((unsigned)f2bf(a.y) << 16);
    o.y = f2bf(a.z) | ((unsigned)f2bf(a.w) << 16);
    o.z = f2bf(b.x) | ((unsigned)f2bf(b.y) << 16);
    o.w = f2bf(b.z) | ((unsigned)f2bf(b.w) << 16);
    return o;
}

// ---------- k1: fused init ------------------------------------------------
// ranges: [0,nH8) h conv | [+nE8) emb conv | +32768 Bpack | +N head=-1
__global__ __launch_bounds__(256) void init_kernel(
    const float4* __restrict__ h4, const float4* __restrict__ emb4,
    const float* __restrict__ Wn, const float* __restrict__ Wl,
    uint4* __restrict__ h8, uint4* __restrict__ emb8,
    ushort* __restrict__ Bpack, int* __restrict__ head,
    int nH8, int nE8, int N)
{
    int i = blockIdx.x * 256 + threadIdx.x;
    if (i < nH8) {
        h8[i] = cvt8(h4[2 * i], h4[2 * i + 1]);
        return;
    }
    int j = i - nH8;
    if (j < nE8) {
        emb8[j] = cvt8(emb4[2 * j], emb4[2 * j + 1]);
        return;
    }
    j -= nE8;
    if (j < 32768) {
        // Bpack[(((nt*8+ks)*64+lane)*8+jj)] = W[ks*32+(lane>>4)*8+jj][nt*16+(lane&15)]
        int jj   = j & 7;
        int lane = (j >> 3) & 63;
        int ks   = (j >> 9) & 7;
        int nt   = j >> 12;
        int k = ks * 32 + (lane >> 4) * 8 + jj;
        int n = nt * 16 + (lane & 15);
        float v = (k < DIM) ? Wn[k * DIM + n] : Wl[(k - DIM) * DIM + n];
        Bpack[j] = f2bf(v);
        return;
    }
    j -= 32768;
    if (j < N) head[j] = -1;
}

// ---------- k2: one-pass linked-list bucketing ----------------------------
// list[e] = { src|etype<<17, prev head }; head[dst] = e.
__global__ __launch_bounds__(256) void build_kernel(
    const int4* __restrict__ src4, const int4* __restrict__ dst4,
    const int4* __restrict__ et4, int* __restrict__ head,
    uint2* __restrict__ list, int E4,
    const int* __restrict__ src, const int* __restrict__ dst,
    const int* __restrict__ etype, int E)
{
    int i = blockIdx.x * 256 + threadIdx.x;
    if (i < E4) {
        int4 s = src4[i], d = dst4[i], t = et4[i];
        int e = 4 * i;
        int old;
        old = atomicExch(head + d.x, e + 0);
        list[e + 0] = make_uint2((unsigned)s.x | ((unsigned)t.x << 17), (unsigned)old);
        old = atomicExch(head + d.y, e + 1);
        list[e + 1] = make_uint2((unsigned)s.y | ((unsigned)t.y << 17), (unsigned)old);
        old = atomicExch(head + d.z, e + 2);
        list[e + 2] = make_uint2((unsigned)s.z | ((unsigned)t.z << 17), (unsigned)old);
        old = atomicExch(head + d.w, e + 3);
        list[e + 3] = make_uint2((unsigned)s.w | ((unsigned)t.w << 17), (unsigned)old);
    }
    if (i == 0)
        for (int e = E4 * 4; e < E; ++e) {
            int old = atomicExch(head + dst[e], e);
            list[e] = make_uint2((unsigned)src[e] | ((unsigned)etype[e] << 17),
                                 (unsigned)old);
        }
}

// ---------- k3: bf16 gather, 2 interleaved chains per 16-lane group --------
__device__ inline void addbf8(float* a, uint4 hv, uint4 rv) {
    a[0] += bf2f((ushort)(hv.x & 0xFFFF)) + bf2f((ushort)(rv.x & 0xFFFF));
    a[1] += bf2f((ushort)(hv.x >> 16))    + bf2f((ushort)(rv.x >> 16));
    a[2] += bf2f((ushort)(hv.y & 0xFFFF)) + bf2f((ushort)(rv.y & 0xFFFF));
    a[3] += bf2f((ushort)(hv.y >> 16))    + bf2f((ushort)(rv.y >> 16));
    a[4] += bf2f((ushort)(hv.z & 0xFFFF)) + bf2f((ushort)(rv.z & 0xFFFF));
    a[5] += bf2f((ushort)(hv.z >> 16))    + bf2f((ushort)(rv.z >> 16));
    a[6] += bf2f((ushort)(hv.w & 0xFFFF)) + bf2f((ushort)(rv.w & 0xFFFF));
    a[7] += bf2f((ushort)(hv.w >> 16))    + bf2f((ushort)(rv.w >> 16));
}
__device__ inline void store8(uint4* aggn8, int n, int lane, const float* a, float nm) {
    uint4 o;
    o.x = f2bf(a[0] * nm) | ((unsigned)f2bf(a[1] * nm) << 16);
    o.y = f2bf(a[2] * nm) | ((unsigned)f2bf(a[3] * nm) << 16);
    o.z = f2bf(a[4] * nm) | ((unsigned)f2bf(a[5] * nm) << 16);
    o.w = f2bf(a[6] * nm) | ((unsigned)f2bf(a[7] * nm) << 16);
    aggn8[(size_t)n * 16 + lane] = o;
}

__global__ __launch_bounds__(256) void gather_kernel(
    const uint4* __restrict__ h8,      // [N][16]
    const uint4* __restrict__ emb8,    // [R][16]
    const float* __restrict__ norm,
    const int* __restrict__ head,
    const uint2* __restrict__ list,
    uint4* __restrict__ aggn8,         // [N][16] bf16
    int N)
{
    int g = blockIdx.x * 16 + (threadIdx.x >> 4);   // group id
    int lane = threadIdx.x & 15;
    int n0 = 2 * g;
    int n1 = 2 * g + 1;
    if (n0 >= N) return;
    bool has1 = (n1 < N);
    int c0 = head[n0];
    int c1 = has1 ? head[n1] : -1;

    float a0[8] = {0.f, 0.f, 0.f, 0.f, 0.f, 0.f, 0.f, 0.f};
    float a1[8] = {0.f, 0.f, 0.f, 0.f, 0.f, 0.f, 0.f, 0.f};

    while ((c0 >= 0) || (c1 >= 0)) {
        bool d0 = (c0 >= 0), d1 = (c1 >= 0);
        uint2 v0, v1;
        uint4 hv0, rv0, hv1, rv1;
        if (d0) v0 = list[c0];
        if (d1) v1 = list[c1];
        if (d0) {
            hv0 = h8[(size_t)(v0.x & 0x1FFFF) * 16 + lane];
            rv0 = emb8[(size_t)(v0.x >> 17) * 16 + lane];
        }
        if (d1) {
            hv1 = h8[(size_t)(v1.x & 0x1FFFF) * 16 + lane];
            rv1 = emb8[(size_t)(v1.x >> 17) * 16 + lane];
        }
        if (d0) { addbf8(a0, hv0, rv0); c0 = (int)v0.y; }
        if (d1) { addbf8(a1, hv1, rv1); c1 = (int)v1.y; }
    }
    store8(aggn8, n0, lane, a0, norm[n0]);
    if (has1) store8(aggn8, n1, lane, a1, norm[n1]);
}

// ---------- k4: MFMA GEMM with fused deg==0 fixup --------------------------
// A = [aggn_bf | h_bf] (N x 256 bf16), B = Bpack ([Wn;Wl], frag layout).
// Wave: 64 cols, B in 128 VGPRs, streams 16-row tiles, 32 MFMA/tile.
// Epilogue: rows with head<0 (no in-edges, expected ~0.3 of 50000) get exact
// fp32 h@We via in-wave slow path.
__global__ __launch_bounds__(256) void mfma_gemm_kernel(
    const ushort* __restrict__ aggn_bf,  // [N][128]
    const ushort* __restrict__ h_bf,     // [N][128]
    const ushort* __restrict__ Bpack,
    const int* __restrict__ head,        // [N]
    const float* __restrict__ hf,        // [N][128] fp32
    const float* __restrict__ We,        // [128][128] fp32
    float* __restrict__ out,             // [N][128]
    int nRowTiles, int halfWaves)
{
    int wave = threadIdx.x >> 6;
    int lane = threadIdx.x & 63;
    int wid  = blockIdx.x * 4 + wave;
    int ch   = wid & 1;                  // column half
    int w    = wid >> 1;
    int m    = lane & 15;
    int quad = lane >> 4;

    bf16x8_t b[4][8];
    #pragma unroll
    for (int nt = 0; nt < 4; ++nt)
        #pragma unroll
        for (int ks = 0; ks < 8; ++ks)
            b[nt][ks] = *(const bf16x8_t*)(Bpack +
                (((size_t)(ch * 4 + nt) * 8 + ks) * 64 + lane) * 8);

    for (int rt = w; rt < nRowTiles; rt += halfWaves) {
        size_t rowOff = (size_t)(rt * 16 + m) * DIM + quad * 8;
        bf16x8_t a[8];
        #pragma unroll
        for (int ks = 0; ks < 4; ++ks) {
            a[ks]     = *(const bf16x8_t*)(aggn_bf + rowOff + ks * 32);
            a[ks + 4] = *(const bf16x8_t*)(h_bf   + rowOff + ks * 32);
        }
        f32x4_t acc[4];
        #pragma unroll
        for (int nt = 0; nt < 4; ++nt)
            #pragma unroll
            for (int r = 0; r < 4; ++r) acc[nt][r] = 0.f;

        #pragma unroll
        for (int ks = 0; ks < 8; ++ks)
            #pragma unroll
            for (int nt = 0; nt < 4; ++nt)
                acc[nt] = __builtin_amdgcn_mfma_f32_16x16x32_bf16(
                    a[ks], b[nt][ks], acc[nt], 0, 0, 0);

        int colBase = ch * 64 + m;
        int rowBase = rt * 16 + quad * 4;
        #pragma unroll
        for (int nt = 0; nt < 4; ++nt)
            #pragma unroll
            for (int r = 0; r < 4; ++r)
                out[(size_t)(rowBase + r) * DIM + colBase + nt * 16] =
                    fmaxf(acc[nt][r], 0.f);

        // fused fixup: rows in this tile with no in-edges -> exact fp32 h@We
        unsigned long long zmask =
            __ballot(head[rt * 16 + (lane & 15)] < 0) & 0xFFFFull;
        while (zmask) {
            int row = __builtin_ctzll(zmask);
            zmask &= zmask - 1;
            int n = rt * 16 + row;
            int c0 = lane * 2;
            float s0 = 0.f, s1 = 0.f;
            for (int k = 0; k < DIM; ++k) {
                float hv = hf[(size_t)n * DIM + k];
                s0 = fmaf(hv, We[(size_t)k * DIM + c0], s0);
                s1 = fmaf(hv, We[(size_t)k * DIM + c0 + 1], s1);
            }
            out[(size_t)n * DIM + c0]     = fmaxf(s0, 0.f);
            out[(size_t)n * DIM + c0 + 1] = fmaxf(s1, 0.f);
        }
    }
}

extern "C" void kernel_launch(void* const* d_in, const int* in_sizes, int n_in,
                              void* d_out, int out_size, void* d_ws, size_t ws_size,
                              hipStream_t stream)
{
    const float* h    = (const float*)d_in[0];
    const float* norm = (const float*)d_in[1];
    const float* emb  = (const float*)d_in[2];
    const float* Wn   = (const float*)d_in[3];
    const float* Wl   = (const float*)d_in[4];
    const float* We   = (const float*)d_in[5];
    const int* src    = (const int*)d_in[6];
    const int* dst    = (const int*)d_in[7];
    const int* etype  = (const int*)d_in[8];

    const int N = in_sizes[1];
    const int E = in_sizes[6];
    const int R = in_sizes[2] / DIM;

    // ws layout (16B-aligned pieces):
    // h_bf[N*128]u16 | emb_bf[R*128]u16 | Bpack[32768]u16 | aggn_bf[N*128]u16
    // | list[E]uint2 | head[N]
    char* p = (char*)d_ws;
    ushort* h_bf    = (ushort*)p;  p += (size_t)N * DIM * 2;
    ushort* emb_bf  = (ushort*)p;  p += (size_t)R * DIM * 2;
    ushort* Bpack   = (ushort*)p;  p += 2 * DIM * DIM * 2;
    ushort* aggn_bf = (ushort*)p;  p += (size_t)N * DIM * 2;
    uint2*  list    = (uint2*)p;   p += (size_t)E * 8;
    int*    head    = (int*)p;

    const int nH8 = N * DIM / 8;
    const int nE8 = R * DIM / 8;
    const int initTotal = nH8 + nE8 + 32768 + N;

    init_kernel<<<dim3((initTotal + 255) / 256), dim3(256), 0, stream>>>(
        (const float4*)h, (const float4*)emb, Wn, Wl,
        (uint4*)h_bf, (uint4*)emb_bf, Bpack, head, nH8, nE8, N);

    build_kernel<<<dim3((E / 4 + 255) / 256), dim3(256), 0, stream>>>(
        (const int4*)src, (const int4*)dst, (const int4*)etype,
        head, list, E / 4, src, dst, etype, E);

    const int nGroups = (N + 1) / 2;
    gather_kernel<<<dim3((nGroups + 15) / 16), dim3(256), 0, stream>>>(
        (const uint4*)h_bf, (const uint4*)emb_bf, norm, head, list,
        (uint4*)aggn_bf, N);

    const int nRowTiles = (N + 15) / 16;     // N=50000 -> 3125 exact
    mfma_gemm_kernel<<<dim3(512), dim3(256), 0, stream>>>(
        aggn_bf, h_bf, Bpack, head, h, We, (float*)d_out, nRowTiles, 1024);
}